// Round 2
// baseline (873.330 us; speedup 1.0000x reference)
//
#include <hip/hip_runtime.h>
#include <stdint.h>

#define NN   100000
#define NE   1600000
#define NG   512
#define HID  128
#define NOUT 64
#define SCAN_B 1024
#define NB   ((NN + SCAN_B - 1) / SCAN_B)   // 98 scan blocks

typedef __bf16 bf16_t;
typedef bf16_t bf16x8 __attribute__((ext_vector_type(8)));
typedef float  f32x4  __attribute__((ext_vector_type(4)));
typedef unsigned int u32;
typedef u32 u32x4 __attribute__((ext_vector_type(4)));
typedef unsigned short u16;

__device__ __forceinline__ u16 f2b(float f) {
    union { float f; u32 u; } v; v.f = f;
    u32 u = v.u + 0x7fffu + ((v.u >> 16) & 1u);   // RNE
    return (u16)(u >> 16);
}
__device__ __forceinline__ float blo(u32 u) {
    union { u32 u; float f; } v; v.u = u << 16; return v.f;
}
__device__ __forceinline__ float bhi(u32 u) {
    union { u32 u; float f; } v; v.u = u & 0xffff0000u; return v.f;
}

// ---------------- CSR build ----------------
__global__ void k_hist(const int* __restrict__ dst, int* __restrict__ cnt) {
    int i = blockIdx.x * blockDim.x + threadIdx.x;
    if (i < NE) atomicAdd(&cnt[dst[i]], 1);
}

__global__ void k_dinv(const int* __restrict__ cnt, const int* __restrict__ batch,
                       float* __restrict__ dinv, int* __restrict__ cntg) {
    int i = blockIdx.x * blockDim.x + threadIdx.x;
    if (i < NN) {
        dinv[i] = rsqrtf((float)(cnt[i] + 1));
        atomicAdd(&cntg[batch[i]], 1);
    }
}

__global__ __launch_bounds__(256) void k_scan1(const int* __restrict__ cnt,
                                               int* __restrict__ rp, int* __restrict__ bsum) {
    __shared__ int sh[256];
    int b = blockIdx.x, t = threadIdx.x;
    int base = b * SCAN_B + t * 4;
    int v[4]; int s = 0;
#pragma unroll
    for (int j = 0; j < 4; j++) { int idx = base + j; v[j] = (idx < NN) ? cnt[idx] : 0; s += v[j]; }
    sh[t] = s; __syncthreads();
    for (int off = 1; off < 256; off <<= 1) {
        int x = (t >= off) ? sh[t - off] : 0;
        __syncthreads();
        sh[t] += x;
        __syncthreads();
    }
    if (t == 255) bsum[b] = sh[255];
    int run = sh[t] - s;
#pragma unroll
    for (int j = 0; j < 4; j++) { int idx = base + j; if (idx < NN) rp[idx] = run; run += v[j]; }
}

__global__ __launch_bounds__(128) void k_scan2(const int* __restrict__ bsum,
                                               int* __restrict__ boff, int* __restrict__ rpN) {
    __shared__ int sh[128];
    int t = threadIdx.x;
    int v = (t < NB) ? bsum[t] : 0;
    sh[t] = v; __syncthreads();
    for (int off = 1; off < 128; off <<= 1) {
        int x = (t >= off) ? sh[t - off] : 0;
        __syncthreads();
        sh[t] += x;
        __syncthreads();
    }
    if (t < NB) boff[t] = sh[t] - v;
    if (t == 127) rpN[0] = sh[127];   // == NE
}

__global__ void k_scan3(int* __restrict__ rp, const int* __restrict__ boff) {
    int i = blockIdx.x * blockDim.x + threadIdx.x;
    if (i < NN) rp[i] += boff[i / SCAN_B];
}

__global__ void k_fill(const int* __restrict__ src, const int* __restrict__ dst,
                       const int* __restrict__ rp, int* __restrict__ cur, int* __restrict__ col) {
    int e = blockIdx.x * blockDim.x + threadIdx.x;
    if (e < NE) {
        int d = dst[e];
        int pos = rp[d] + atomicAdd(&cur[d], 1);
        col[pos] = src[e];
    }
}

// ---------------- weight pack (fragment order) ----------------
__global__ void k_pack(const float* __restrict__ W, u16* __restrict__ Wp) {
    int tid = blockIdx.x * blockDim.x + threadIdx.x;
    if (tid >= 32 * 64) return;
    int f = tid >> 6, l = tid & 63;
    int c = f >> 2, s = f & 3;
    int n  = c * 16 + (l & 15);
    int k0 = s * 32 + ((l >> 4) << 3);
#pragma unroll
    for (int j = 0; j < 8; j++) Wp[tid * 8 + j] = f2b(W[(k0 + j) * HID + n]);
}

// ---------------- GEMM: h = X @ W, out g = bf16(h * dinv[row]) ----------------
template<int INF32>
__global__ __launch_bounds__(256) void k_gemm(const void* __restrict__ Xin,
                                              const u16* __restrict__ Wp,
                                              const float* __restrict__ dinv,
                                              u16* __restrict__ Gout) {
    int w = threadIdx.x >> 6, l = threadIdx.x & 63;
    int r0  = blockIdx.x * 64 + w * 16;
    int l15 = l & 15, lh = l >> 4;
    int arow = r0 + l15;
    int arc  = (arow < NN) ? arow : (NN - 1);

    const float* Xf = (const float*)Xin;
    const u16*   Xh = (const u16*)Xin;

    f32x4 acc[8];
#pragma unroll
    for (int c = 0; c < 8; c++) acc[c] = (f32x4){0.f, 0.f, 0.f, 0.f};

#pragma unroll
    for (int s = 0; s < 4; s++) {
        int k0 = s * 32 + lh * 8;
        bf16x8 a;
        if (INF32) {
            f32x4 p0 = *(const f32x4*)(Xf + arc * HID + k0);
            f32x4 p1 = *(const f32x4*)(Xf + arc * HID + k0 + 4);
            union { bf16x8 v; u16 h[8]; } au;
#pragma unroll
            for (int j = 0; j < 4; j++) { au.h[j] = f2b(p0[j]); au.h[j + 4] = f2b(p1[j]); }
            a = au.v;
        } else {
            a = *(const bf16x8*)(Xh + arc * HID + k0);
        }
#pragma unroll
        for (int c = 0; c < 8; c++) {
            bf16x8 b = *(const bf16x8*)(Wp + ((c * 4 + s) * 64 + l) * 8);
            acc[c] = __builtin_amdgcn_mfma_f32_16x16x32_bf16(a, b, acc[c], 0, 0, 0);
        }
    }
#pragma unroll
    for (int q = 0; q < 4; q++) {
        int row = r0 + lh * 4 + q;
        if (row < NN) {
            float dv = dinv[row];
#pragma unroll
            for (int c = 0; c < 8; c++) {
                Gout[row * HID + c * 16 + l15] = f2b(acc[c][q] * dv);
            }
        }
    }
}

// ---------------- aggregation: one wave per node, 4 edge-groups x 16 lanes ----------------
// Group q (lanes q*16..q*16+15) gathers a whole 256B row per load (16 lanes x 16B).
// 4 loads per iteration => 16 edges in flight. Lane (l&15) owns features [l15*8, l15*8+8).
template<int LAYER>
__global__ __launch_bounds__(256) void k_agg(const u16* __restrict__ g,
                                             const int* __restrict__ rp,
                                             const int* __restrict__ col,
                                             const float* __restrict__ dinv,
                                             const float* __restrict__ bias,
                                             u16* __restrict__ tout,
                                             const int* __restrict__ batch,
                                             float* __restrict__ psum) {
    int w = threadIdx.x >> 6, l = threadIdx.x & 63;
    int v = blockIdx.x * 4 + w;
    if (v >= NN) return;
    int q   = l >> 4;
    int l15 = l & 15;
    const u16* rb = g + (size_t)l15 * 8;   // this lane's 16B chunk within any row

    float a0 = 0.f, a1 = 0.f, a2 = 0.f, a3 = 0.f, a4 = 0.f, a5 = 0.f, a6 = 0.f, a7 = 0.f;

#define ACCR(r, mk) do { \
    a0 = fmaf(mk, blo((r).x), a0); a1 = fmaf(mk, bhi((r).x), a1); \
    a2 = fmaf(mk, blo((r).y), a2); a3 = fmaf(mk, bhi((r).y), a3); \
    a4 = fmaf(mk, blo((r).z), a4); a5 = fmaf(mk, bhi((r).z), a5); \
    a6 = fmaf(mk, blo((r).w), a6); a7 = fmaf(mk, bhi((r).w), a7); } while (0)

    int e = rp[v], end = rp[v + 1];
    while (e < end) {
        int m = end - e; if (m > 64) m = 64;
        int ci = col[e + ((l < m) ? l : (m - 1))];
        for (int j = 0; j < m; j += 16) {
            int j0 = j + q, j1 = j + 4 + q, j2 = j + 8 + q, j3 = j + 12 + q;
            int i0 = __shfl(ci, (j0 < m) ? j0 : (m - 1));
            int i1 = __shfl(ci, (j1 < m) ? j1 : (m - 1));
            int i2 = __shfl(ci, (j2 < m) ? j2 : (m - 1));
            int i3 = __shfl(ci, (j3 < m) ? j3 : (m - 1));
            u32x4 r0 = *(const u32x4*)(rb + (size_t)i0 * HID);
            u32x4 r1 = *(const u32x4*)(rb + (size_t)i1 * HID);
            u32x4 r2 = *(const u32x4*)(rb + (size_t)i2 * HID);
            u32x4 r3 = *(const u32x4*)(rb + (size_t)i3 * HID);
            float m0 = (j0 < m) ? 1.f : 0.f;
            float m1 = (j1 < m) ? 1.f : 0.f;
            float m2 = (j2 < m) ? 1.f : 0.f;
            float m3 = (j3 < m) ? 1.f : 0.f;
            ACCR(r0, m0); ACCR(r1, m1); ACCR(r2, m2); ACCR(r3, m3);
        }
        e += m;
    }
#undef ACCR

    // cross-group reduce (lanes l, l^16, l^32 hold same features)
    a0 += __shfl_xor(a0, 16); a0 += __shfl_xor(a0, 32);
    a1 += __shfl_xor(a1, 16); a1 += __shfl_xor(a1, 32);
    a2 += __shfl_xor(a2, 16); a2 += __shfl_xor(a2, 32);
    a3 += __shfl_xor(a3, 16); a3 += __shfl_xor(a3, 32);
    a4 += __shfl_xor(a4, 16); a4 += __shfl_xor(a4, 32);
    a5 += __shfl_xor(a5, 16); a5 += __shfl_xor(a5, 32);
    a6 += __shfl_xor(a6, 16); a6 += __shfl_xor(a6, 32);
    a7 += __shfl_xor(a7, 16); a7 += __shfl_xor(a7, 32);

    // self-loop (same value added in every group copy -> stays consistent)
    u32x4 sv = *(const u32x4*)(rb + (size_t)v * HID);
    a0 += blo(sv.x); a1 += bhi(sv.x); a2 += blo(sv.y); a3 += bhi(sv.y);
    a4 += blo(sv.z); a5 += bhi(sv.z); a6 += blo(sv.w); a7 += bhi(sv.w);

    float dv = dinv[v];
    f32x4 bb0 = *(const f32x4*)(bias + l15 * 8);
    f32x4 bb1 = *(const f32x4*)(bias + l15 * 8 + 4);
    float o0 = a0 * dv + bb0[0], o1 = a1 * dv + bb0[1];
    float o2 = a2 * dv + bb0[2], o3 = a3 * dv + bb0[3];
    float o4 = a4 * dv + bb1[0], o5 = a5 * dv + bb1[1];
    float o6 = a6 * dv + bb1[2], o7 = a7 * dv + bb1[3];

    if (LAYER == 1) {
        o0 = fmaxf(o0, 0.f); o1 = fmaxf(o1, 0.f); o2 = fmaxf(o2, 0.f); o3 = fmaxf(o3, 0.f);
        o4 = fmaxf(o4, 0.f); o5 = fmaxf(o5, 0.f); o6 = fmaxf(o6, 0.f); o7 = fmaxf(o7, 0.f);
        if (q == 0) {
            u32x4 pk;
            pk.x = (u32)f2b(o0) | ((u32)f2b(o1) << 16);
            pk.y = (u32)f2b(o2) | ((u32)f2b(o3) << 16);
            pk.z = (u32)f2b(o4) | ((u32)f2b(o5) << 16);
            pk.w = (u32)f2b(o6) | ((u32)f2b(o7) << 16);
            *(u32x4*)(tout + (size_t)v * HID + l15 * 8) = pk;
        }
    } else {
        if (q == 0) {
            int bg = batch[v];
            float* ps = psum + (size_t)bg * HID + l15 * 8;
            atomicAdd(ps + 0, o0); atomicAdd(ps + 1, o1);
            atomicAdd(ps + 2, o2); atomicAdd(ps + 3, o3);
            atomicAdd(ps + 4, o4); atomicAdd(ps + 5, o5);
            atomicAdd(ps + 6, o6); atomicAdd(ps + 7, o7);
        }
    }
}

// ---------------- pooled FC ----------------
__global__ __launch_bounds__(64) void k_fc(const float* __restrict__ psum,
                                           const int* __restrict__ cntg,
                                           const float* __restrict__ Wfc,
                                           const float* __restrict__ bfc,
                                           float* __restrict__ out) {
    __shared__ float pooled[HID];
    int gph = blockIdx.x, t = threadIdx.x;
    float inv = 1.f / fmaxf((float)cntg[gph], 1.f);
    for (int k = t; k < HID; k += 64) pooled[k] = psum[gph * HID + k] * inv;
    __syncthreads();
    float acc = bfc[t];
    for (int k = 0; k < HID; k++) acc += pooled[k] * Wfc[k * NOUT + t];
    out[gph * NOUT + t] = acc;
}

extern "C" void kernel_launch(void* const* d_in, const int* in_sizes, int n_in,
                              void* d_out, int out_size, void* d_ws, size_t ws_size,
                              hipStream_t stream) {
    const float* x     = (const float*)d_in[0];
    const int*   ei    = (const int*)d_in[1];
    const int*   batch = (const int*)d_in[3];
    const float* W1    = (const float*)d_in[4];
    const float* b1    = (const float*)d_in[5];
    const float* W2    = (const float*)d_in[6];
    const float* b2    = (const float*)d_in[7];
    const float* Wfc   = (const float*)d_in[8];
    const float* bfc   = (const float*)d_in[9];
    float* out = (float*)d_out;

    const int* src = ei;
    const int* dst = ei + NE;

    char* p = (char*)d_ws;
    auto take = [&](size_t bytes) { char* r = p; p += (bytes + 255) & ~(size_t)255; return r; };
    int*   cnt  = (int*)take((size_t)NN * 4);
    int*   cur  = (int*)take((size_t)NN * 4);
    int*   rp   = (int*)take((size_t)(NN + 1) * 4);
    int*   bsum = (int*)take(256 * 4);
    int*   boff = (int*)take(256 * 4);
    float* dinv = (float*)take((size_t)NN * 4);
    int*   cntg = (int*)take((size_t)NG * 4);
    float* psum = (float*)take((size_t)NG * HID * 4);
    u16*   Wp1  = (u16*)take((size_t)32 * 64 * 8 * 2);
    u16*   Wp2  = (u16*)take((size_t)32 * 64 * 8 * 2);
    int*   col  = (int*)take((size_t)NE * 4);
    u16*   g    = (u16*)take((size_t)NN * HID * 2);
    u16*   t    = (u16*)take((size_t)NN * HID * 2);

    hipMemsetAsync(cnt,  0, (size_t)NN * 4, stream);
    hipMemsetAsync(cur,  0, (size_t)NN * 4, stream);
    hipMemsetAsync(cntg, 0, (size_t)NG * 4, stream);
    hipMemsetAsync(psum, 0, (size_t)NG * HID * 4, stream);

    k_hist <<<(NE + 255) / 256, 256, 0, stream>>>(dst, cnt);
    k_dinv <<<(NN + 255) / 256, 256, 0, stream>>>(cnt, batch, dinv, cntg);
    k_scan1<<<NB, 256, 0, stream>>>(cnt, rp, bsum);
    k_scan2<<<1, 128, 0, stream>>>(bsum, boff, rp + NN);
    k_scan3<<<(NN + 255) / 256, 256, 0, stream>>>(rp, boff);
    k_fill <<<(NE + 255) / 256, 256, 0, stream>>>(src, dst, rp, cur, col);
    k_pack <<<8, 256, 0, stream>>>(W1, Wp1);
    k_pack <<<8, 256, 0, stream>>>(W2, Wp2);

    k_gemm<1><<<(NN + 63) / 64, 256, 0, stream>>>((const void*)x, Wp1, dinv, g);
    k_agg<1> <<<(NN + 3) / 4, 256, 0, stream>>>(g, rp, col, dinv, b1, t, nullptr, nullptr);
    k_gemm<0><<<(NN + 63) / 64, 256, 0, stream>>>((const void*)t, Wp2, dinv, g);
    k_agg<2> <<<(NN + 3) / 4, 256, 0, stream>>>(g, rp, col, dinv, b2, nullptr, batch, psum);
    k_fc   <<<NG, 64, 0, stream>>>(psum, cntg, Wfc, bfc, out);
}

// Round 3
// 468.514 us; speedup vs baseline: 1.8640x; 1.8640x over previous
//
#include <hip/hip_runtime.h>
#include <stdint.h>

#define NN   100000
#define NE   1600000
#define NG   512
#define HID  128
#define NOUT 64
#define SCAN_B 1024
#define NB   ((NN + SCAN_B - 1) / SCAN_B)   // 98 scan blocks

typedef __bf16 bf16_t;
typedef bf16_t bf16x8 __attribute__((ext_vector_type(8)));
typedef float  f32x4  __attribute__((ext_vector_type(4)));
typedef unsigned int u32;
typedef unsigned short u16;

__device__ __forceinline__ u16 f2b(float f) {
    union { float f; u32 u; } v; v.f = f;
    u32 u = v.u + 0x7fffu + ((v.u >> 16) & 1u);   // RNE
    return (u16)(u >> 16);
}
__device__ __forceinline__ float blo(u32 u) {
    union { u32 u; float f; } v; v.u = u << 16; return v.f;
}
__device__ __forceinline__ float bhi(u32 u) {
    union { u32 u; float f; } v; v.u = u & 0xffff0000u; return v.f;
}

// ---------------- CSR build ----------------
__global__ void k_hist(const int* __restrict__ dst, int* __restrict__ cnt) {
    int i = blockIdx.x * blockDim.x + threadIdx.x;
    if (i < NE) atomicAdd(&cnt[dst[i]], 1);
}

__global__ void k_dinv(const int* __restrict__ cnt, const int* __restrict__ batch,
                       float* __restrict__ dinv, int* __restrict__ cntg) {
    int i = blockIdx.x * blockDim.x + threadIdx.x;
    if (i < NN) {
        dinv[i] = rsqrtf((float)(cnt[i] + 1));
        atomicAdd(&cntg[batch[i]], 1);
    }
}

__global__ __launch_bounds__(256) void k_scan1(const int* __restrict__ cnt,
                                               int* __restrict__ rp, int* __restrict__ bsum) {
    __shared__ int sh[256];
    int b = blockIdx.x, t = threadIdx.x;
    int base = b * SCAN_B + t * 4;
    int v[4]; int s = 0;
#pragma unroll
    for (int j = 0; j < 4; j++) { int idx = base + j; v[j] = (idx < NN) ? cnt[idx] : 0; s += v[j]; }
    sh[t] = s; __syncthreads();
    for (int off = 1; off < 256; off <<= 1) {
        int x = (t >= off) ? sh[t - off] : 0;
        __syncthreads();
        sh[t] += x;
        __syncthreads();
    }
    if (t == 255) bsum[b] = sh[255];
    int run = sh[t] - s;
#pragma unroll
    for (int j = 0; j < 4; j++) { int idx = base + j; if (idx < NN) rp[idx] = run; run += v[j]; }
}

__global__ __launch_bounds__(128) void k_scan2(const int* __restrict__ bsum,
                                               int* __restrict__ boff, int* __restrict__ rpN) {
    __shared__ int sh[128];
    int t = threadIdx.x;
    int v = (t < NB) ? bsum[t] : 0;
    sh[t] = v; __syncthreads();
    for (int off = 1; off < 128; off <<= 1) {
        int x = (t >= off) ? sh[t - off] : 0;
        __syncthreads();
        sh[t] += x;
        __syncthreads();
    }
    if (t < NB) boff[t] = sh[t] - v;
    if (t == 127) rpN[0] = sh[127];   // == NE
}

__global__ void k_scan3(int* __restrict__ rp, const int* __restrict__ boff) {
    int i = blockIdx.x * blockDim.x + threadIdx.x;
    if (i < NN) rp[i] += boff[i / SCAN_B];
}

__global__ void k_fill(const int* __restrict__ src, const int* __restrict__ dst,
                       const int* __restrict__ rp, int* __restrict__ cur, int* __restrict__ col) {
    int e = blockIdx.x * blockDim.x + threadIdx.x;
    if (e < NE) {
        int d = dst[e];
        int pos = rp[d] + atomicAdd(&cur[d], 1);
        col[pos] = src[e];
    }
}

// ---------------- weight pack (fragment order) ----------------
__global__ void k_pack(const float* __restrict__ W, u16* __restrict__ Wp) {
    int tid = blockIdx.x * blockDim.x + threadIdx.x;
    if (tid >= 32 * 64) return;
    int f = tid >> 6, l = tid & 63;
    int c = f >> 2, s = f & 3;
    int n  = c * 16 + (l & 15);
    int k0 = s * 32 + ((l >> 4) << 3);
#pragma unroll
    for (int j = 0; j < 8; j++) Wp[tid * 8 + j] = f2b(W[(k0 + j) * HID + n]);
}

// ---------------- GEMM: h = X @ W, out g = bf16(h * dinv[row]) ----------------
template<int INF32>
__global__ __launch_bounds__(256) void k_gemm(const void* __restrict__ Xin,
                                              const u16* __restrict__ Wp,
                                              const float* __restrict__ dinv,
                                              u16* __restrict__ Gout) {
    int w = threadIdx.x >> 6, l = threadIdx.x & 63;
    int r0  = blockIdx.x * 64 + w * 16;
    int l15 = l & 15, lh = l >> 4;
    int arow = r0 + l15;
    int arc  = (arow < NN) ? arow : (NN - 1);

    const float* Xf = (const float*)Xin;
    const u16*   Xh = (const u16*)Xin;

    f32x4 acc[8];
#pragma unroll
    for (int c = 0; c < 8; c++) acc[c] = (f32x4){0.f, 0.f, 0.f, 0.f};

#pragma unroll
    for (int s = 0; s < 4; s++) {
        int k0 = s * 32 + lh * 8;
        bf16x8 a;
        if (INF32) {
            f32x4 p0 = *(const f32x4*)(Xf + arc * HID + k0);
            f32x4 p1 = *(const f32x4*)(Xf + arc * HID + k0 + 4);
            union { bf16x8 v; u16 h[8]; } au;
#pragma unroll
            for (int j = 0; j < 4; j++) { au.h[j] = f2b(p0[j]); au.h[j + 4] = f2b(p1[j]); }
            a = au.v;
        } else {
            a = *(const bf16x8*)(Xh + arc * HID + k0);
        }
#pragma unroll
        for (int c = 0; c < 8; c++) {
            bf16x8 b = *(const bf16x8*)(Wp + ((c * 4 + s) * 64 + l) * 8);
            acc[c] = __builtin_amdgcn_mfma_f32_16x16x32_bf16(a, b, acc[c], 0, 0, 0);
        }
    }
#pragma unroll
    for (int q = 0; q < 4; q++) {
        int row = r0 + lh * 4 + q;
        if (row < NN) {
            float dv = dinv[row];
#pragma unroll
            for (int c = 0; c < 8; c++) {
                Gout[row * HID + c * 16 + l15] = f2b(acc[c][q] * dv);
            }
        }
    }
}

// ---------------- aggregation: one wave per node, lane owns 2 features ----------------
// One u32 load per lane per row (64 lanes x 4B = full 256B row, coalesced).
// 8 independent rows in flight per iteration; masked FMA handles the tail.
template<int LAYER>
__global__ __launch_bounds__(256) void k_agg(const u16* __restrict__ g,
                                             const int* __restrict__ rp,
                                             const int* __restrict__ col,
                                             const float* __restrict__ dinv,
                                             const float* __restrict__ bias,
                                             u16* __restrict__ tout,
                                             const int* __restrict__ batch,
                                             float* __restrict__ psum) {
    int w = threadIdx.x >> 6, l = threadIdx.x & 63;
    int v = blockIdx.x * 4 + w;
    if (v >= NN) return;
    int f0 = 2 * l;
    const u16* gl = g + f0;   // this lane's 4B column within any row

    // self loop: g[v]
    u32 u = *(const u32*)(gl + (size_t)v * HID);
    float a0 = blo(u), a1 = bhi(u);

    int e = rp[v], end = rp[v + 1];
    while (e < end) {
        int m = end - e; if (m > 64) m = 64;
        int ci = col[e + ((l < m) ? l : (m - 1))];
        for (int j = 0; j < m; j += 8) {
            int i0 = __shfl(ci, (j     < m) ? j     : (m - 1));
            int i1 = __shfl(ci, (j + 1 < m) ? j + 1 : (m - 1));
            int i2 = __shfl(ci, (j + 2 < m) ? j + 2 : (m - 1));
            int i3 = __shfl(ci, (j + 3 < m) ? j + 3 : (m - 1));
            int i4 = __shfl(ci, (j + 4 < m) ? j + 4 : (m - 1));
            int i5 = __shfl(ci, (j + 5 < m) ? j + 5 : (m - 1));
            int i6 = __shfl(ci, (j + 6 < m) ? j + 6 : (m - 1));
            int i7 = __shfl(ci, (j + 7 < m) ? j + 7 : (m - 1));
            u32 u0 = *(const u32*)(gl + (size_t)i0 * HID);
            u32 u1 = *(const u32*)(gl + (size_t)i1 * HID);
            u32 u2 = *(const u32*)(gl + (size_t)i2 * HID);
            u32 u3 = *(const u32*)(gl + (size_t)i3 * HID);
            u32 u4 = *(const u32*)(gl + (size_t)i4 * HID);
            u32 u5 = *(const u32*)(gl + (size_t)i5 * HID);
            u32 u6 = *(const u32*)(gl + (size_t)i6 * HID);
            u32 u7 = *(const u32*)(gl + (size_t)i7 * HID);
            float m1f = (j + 1 < m) ? 1.f : 0.f;
            float m2f = (j + 2 < m) ? 1.f : 0.f;
            float m3f = (j + 3 < m) ? 1.f : 0.f;
            float m4f = (j + 4 < m) ? 1.f : 0.f;
            float m5f = (j + 5 < m) ? 1.f : 0.f;
            float m6f = (j + 6 < m) ? 1.f : 0.f;
            float m7f = (j + 7 < m) ? 1.f : 0.f;
            a0 += blo(u0);               a1 += bhi(u0);
            a0 = fmaf(m1f, blo(u1), a0); a1 = fmaf(m1f, bhi(u1), a1);
            a0 = fmaf(m2f, blo(u2), a0); a1 = fmaf(m2f, bhi(u2), a1);
            a0 = fmaf(m3f, blo(u3), a0); a1 = fmaf(m3f, bhi(u3), a1);
            a0 = fmaf(m4f, blo(u4), a0); a1 = fmaf(m4f, bhi(u4), a1);
            a0 = fmaf(m5f, blo(u5), a0); a1 = fmaf(m5f, bhi(u5), a1);
            a0 = fmaf(m6f, blo(u6), a0); a1 = fmaf(m6f, bhi(u6), a1);
            a0 = fmaf(m7f, blo(u7), a0); a1 = fmaf(m7f, bhi(u7), a1);
        }
        e += m;
    }

    float dv = dinv[v];
    float o0 = a0 * dv + bias[f0];
    float o1 = a1 * dv + bias[f0 + 1];
    if (LAYER == 1) {
        o0 = fmaxf(o0, 0.f); o1 = fmaxf(o1, 0.f);
        u32 outp = (u32)f2b(o0) | ((u32)f2b(o1) << 16);
        *(u32*)(tout + (size_t)v * HID + f0) = outp;
    } else {
        int bg = batch[v];
        atomicAdd(&psum[(size_t)bg * HID + f0],     o0);
        atomicAdd(&psum[(size_t)bg * HID + f0 + 1], o1);
    }
}

// ---------------- pooled FC ----------------
__global__ __launch_bounds__(64) void k_fc(const float* __restrict__ psum,
                                           const int* __restrict__ cntg,
                                           const float* __restrict__ Wfc,
                                           const float* __restrict__ bfc,
                                           float* __restrict__ out) {
    __shared__ float pooled[HID];
    int gph = blockIdx.x, t = threadIdx.x;
    float inv = 1.f / fmaxf((float)cntg[gph], 1.f);
    for (int k = t; k < HID; k += 64) pooled[k] = psum[gph * HID + k] * inv;
    __syncthreads();
    float acc = bfc[t];
    for (int k = 0; k < HID; k++) acc += pooled[k] * Wfc[k * NOUT + t];
    out[gph * NOUT + t] = acc;
}

extern "C" void kernel_launch(void* const* d_in, const int* in_sizes, int n_in,
                              void* d_out, int out_size, void* d_ws, size_t ws_size,
                              hipStream_t stream) {
    const float* x     = (const float*)d_in[0];
    const int*   ei    = (const int*)d_in[1];
    const int*   batch = (const int*)d_in[3];
    const float* W1    = (const float*)d_in[4];
    const float* b1    = (const float*)d_in[5];
    const float* W2    = (const float*)d_in[6];
    const float* b2    = (const float*)d_in[7];
    const float* Wfc   = (const float*)d_in[8];
    const float* bfc   = (const float*)d_in[9];
    float* out = (float*)d_out;

    const int* src = ei;
    const int* dst = ei + NE;

    char* p = (char*)d_ws;
    auto take = [&](size_t bytes) { char* r = p; p += (bytes + 255) & ~(size_t)255; return r; };
    int*   cnt  = (int*)take((size_t)NN * 4);
    int*   cur  = (int*)take((size_t)NN * 4);
    int*   rp   = (int*)take((size_t)(NN + 1) * 4);
    int*   bsum = (int*)take(256 * 4);
    int*   boff = (int*)take(256 * 4);
    float* dinv = (float*)take((size_t)NN * 4);
    int*   cntg = (int*)take((size_t)NG * 4);
    float* psum = (float*)take((size_t)NG * HID * 4);
    u16*   Wp1  = (u16*)take((size_t)32 * 64 * 8 * 2);
    u16*   Wp2  = (u16*)take((size_t)32 * 64 * 8 * 2);
    int*   col  = (int*)take((size_t)NE * 4);
    u16*   g    = (u16*)take((size_t)NN * HID * 2);
    u16*   t    = (u16*)take((size_t)NN * HID * 2);

    hipMemsetAsync(cnt,  0, (size_t)NN * 4, stream);
    hipMemsetAsync(cur,  0, (size_t)NN * 4, stream);
    hipMemsetAsync(cntg, 0, (size_t)NG * 4, stream);
    hipMemsetAsync(psum, 0, (size_t)NG * HID * 4, stream);

    k_hist <<<(NE + 255) / 256, 256, 0, stream>>>(dst, cnt);
    k_dinv <<<(NN + 255) / 256, 256, 0, stream>>>(cnt, batch, dinv, cntg);
    k_scan1<<<NB, 256, 0, stream>>>(cnt, rp, bsum);
    k_scan2<<<1, 128, 0, stream>>>(bsum, boff, rp + NN);
    k_scan3<<<(NN + 255) / 256, 256, 0, stream>>>(rp, boff);
    k_fill <<<(NE + 255) / 256, 256, 0, stream>>>(src, dst, rp, cur, col);
    k_pack <<<8, 256, 0, stream>>>(W1, Wp1);
    k_pack <<<8, 256, 0, stream>>>(W2, Wp2);

    k_gemm<1><<<(NN + 63) / 64, 256, 0, stream>>>((const void*)x, Wp1, dinv, g);
    k_agg<1> <<<(NN + 3) / 4, 256, 0, stream>>>(g, rp, col, dinv, b1, t, nullptr, nullptr);
    k_gemm<0><<<(NN + 63) / 64, 256, 0, stream>>>((const void*)t, Wp2, dinv, g);
    k_agg<2> <<<(NN + 3) / 4, 256, 0, stream>>>(g, rp, col, dinv, b2, nullptr, batch, psum);
    k_fc   <<<NG, 64, 0, stream>>>(psum, cntg, Wfc, bfc, out);
}